// Round 1
// baseline (6658.704 us; speedup 1.0000x reference)
//
#include <hip/hip_runtime.h>

// Seq2Seq GRU + Bahdanau attention, fp32 reference-faithful implementation.
// B=32 S=64 T=48 E=512 H=1024 V=32000.
//
// Structure:
//  - enc_gi  = gather(enc_embed, src) @ enc_w_ih^T + b_ih      (one GEMM, all steps)
//  - 64x fused encoder GRU step kernels (h kept transposed/packed for coalescing)
//  - keys    = enc_out @ wk^T + bk                             (one GEMM)
//  - dec_gi  = gather(dec_embed, dec_in) @ dec_w_ih[:, :E]^T + b_ih (one GEMM)
//  - 47x (q-proj, attention+softmax+ctx, fused GRU step w/ ctx@W_ih[:,E:] folded in)
//  - logits  = h2_all @ wo^T + bo  (single big GEMM, rows permuted t-major -> b-major)

#define BB 32
#define SS 64
#define TT 48
#define TD 47
#define EE 512
#define HH 1024
#define GG 3072
#define VV 32000
#define SOS_IDX 1

static __device__ __forceinline__ float sigmoid_f(float x) {
    return 1.0f / (1.0f + __expf(-x));
}
static __device__ __forceinline__ float tanh_f(float x) {
    // 1 - 2/(e^{2x}+1); saturates correctly at +/-inf
    return 1.0f - 2.0f / (__expf(2.0f * x) + 1.0f);
}

__global__ void k_zero(float* p, int n) {
    int i = blockIdx.x * 256 + threadIdx.x;
    if (i < n) p[i] = 0.f;
}

__global__ void k_dec_idx(const int* __restrict__ tgt, int* __restrict__ idx) {
    int m = blockIdx.x * 256 + threadIdx.x;
    if (m < TD * BB) {
        int t = m >> 5, b = m & 31;
        idx[m] = (t == 0) ? SOS_IDX : tgt[b * TT + t];
    }
}

// C[m,n] = sum_k A[row(m),k] * Wt[n,k] + bias[n]
// row(m) = rowidx ? rowidx[m] : m.  permute=1: output row = (m%32)*47 + m/32.
__global__ __launch_bounds__(256) void k_gemm(
    const float* __restrict__ A, const float* __restrict__ Wt,
    const float* __restrict__ bias, float* __restrict__ C,
    const int* __restrict__ rowidx,
    int M, int N, int K, int lda, int ldw, int ldc, int permute)
{
    __shared__ __align__(16) float As[16][64];
    __shared__ __align__(16) float Bs[16][64];
    const int tid = threadIdx.x;
    const int tm = tid >> 4;      // 0..15
    const int tn = tid & 15;      // 0..15
    const int row0 = blockIdx.y * 64;
    const int col0 = blockIdx.x * 64;
    const int lr = tid >> 2;      // 0..63
    const int lq = tid & 3;       // 0..3

    long arow_off = -1;
    {
        int arow = row0 + lr;
        if (arow < M) {
            int r = rowidx ? rowidx[arow] : arow;
            arow_off = (long)r * lda;
        }
    }
    long wrow_off = -1;
    {
        int wcol = col0 + lr;
        if (wcol < N) wrow_off = (long)wcol * ldw;
    }

    float acc[4][4];
#pragma unroll
    for (int i = 0; i < 4; ++i)
#pragma unroll
        for (int j = 0; j < 4; ++j) acc[i][j] = 0.f;

    for (int k0 = 0; k0 < K; k0 += 16) {
        float4 av = make_float4(0.f, 0.f, 0.f, 0.f);
        if (arow_off >= 0) av = *(const float4*)(A + arow_off + k0 + lq * 4);
        float4 wv = make_float4(0.f, 0.f, 0.f, 0.f);
        if (wrow_off >= 0) wv = *(const float4*)(Wt + wrow_off + k0 + lq * 4);
        __syncthreads();
        As[lq * 4 + 0][lr] = av.x; As[lq * 4 + 1][lr] = av.y;
        As[lq * 4 + 2][lr] = av.z; As[lq * 4 + 3][lr] = av.w;
        Bs[lq * 4 + 0][lr] = wv.x; Bs[lq * 4 + 1][lr] = wv.y;
        Bs[lq * 4 + 2][lr] = wv.z; Bs[lq * 4 + 3][lr] = wv.w;
        __syncthreads();
#pragma unroll
        for (int kk = 0; kk < 16; ++kk) {
            float4 a4 = *(const float4*)&As[kk][tm * 4];
            float4 b4 = *(const float4*)&Bs[kk][tn * 4];
            acc[0][0] += a4.x * b4.x; acc[0][1] += a4.x * b4.y;
            acc[0][2] += a4.x * b4.z; acc[0][3] += a4.x * b4.w;
            acc[1][0] += a4.y * b4.x; acc[1][1] += a4.y * b4.y;
            acc[1][2] += a4.y * b4.z; acc[1][3] += a4.y * b4.w;
            acc[2][0] += a4.z * b4.x; acc[2][1] += a4.z * b4.y;
            acc[2][2] += a4.z * b4.z; acc[2][3] += a4.z * b4.w;
            acc[3][0] += a4.w * b4.x; acc[3][1] += a4.w * b4.y;
            acc[3][2] += a4.w * b4.z; acc[3][3] += a4.w * b4.w;
        }
    }

    float4 bv = make_float4(0.f, 0.f, 0.f, 0.f);
    if (bias) bv = *(const float4*)(bias + col0 + tn * 4);
#pragma unroll
    for (int i = 0; i < 4; ++i) {
        int m = row0 + tm * 4 + i;
        if (m >= M) continue;
        int orow = permute ? ((m & 31) * TD + (m >> 5)) : m;
        float4 v;
        v.x = acc[i][0] + bv.x; v.y = acc[i][1] + bv.y;
        v.z = acc[i][2] + bv.z; v.w = acc[i][3] + bv.w;
        *(float4*)(C + (long)orow * ldc + col0 + tn * 4) = v;
    }
}

// One fused GRU step. hT4 layout: element (k,b) at [(k>>2)*128 + b*4 + (k&3)].
// grid = H/2 blocks of 256 threads; thread = (b, k-split ks, j-lane jl).
// gi row for batch b is (gi_off + b*gi_bstride); gi holds input-projection (+b_ih).
// If ctxT4 != null (decoder): also accumulates ctx @ Wih[:, E:]^T (Wih row stride E+H).
// Writes new h into hT4_out and into extra_out[(gi_row)*H + j].
__global__ __launch_bounds__(256) void k_gru_step(
    const float* __restrict__ hT4_in, float* __restrict__ hT4_out,
    const float* __restrict__ gi, int gi_off, int gi_bstride,
    const float* __restrict__ Whh, const float* __restrict__ bhh,
    const float* __restrict__ ctxT4, const float* __restrict__ Wih,
    float* __restrict__ extra_out)
{
    const int tid = threadIdx.x;
    const int b  = tid & 31;
    const int ks = (tid >> 5) & 3;
    const int jl = tid >> 7;            // 0..1
    const int j  = blockIdx.x * 2 + jl;
    const int kc = ks * 256;

    const float* hb = hT4_in + (kc >> 2) * (BB * 4) + b * 4;
    const float* wr = Whh + (long)j * HH + kc;
    const float* wz = wr + (long)HH * HH;
    const float* wn = wz + (long)HH * HH;

    float ar = 0.f, az = 0.f, an = 0.f, cr = 0.f, cz = 0.f, cn = 0.f;
    if (ctxT4) {
        const float* cb = ctxT4 + (kc >> 2) * (BB * 4) + b * 4;
        const float* vr = Wih + (long)j * (EE + HH) + EE + kc;
        const float* vz = vr + (long)HH * (EE + HH);
        const float* vn = vz + (long)HH * (EE + HH);
        for (int i = 0; i < 64; ++i) {
            float4 h4 = *(const float4*)(hb + i * 128);
            float4 c4 = *(const float4*)(cb + i * 128);
            float4 w;
            w = *(const float4*)(wr + i * 4);
            ar += h4.x * w.x + h4.y * w.y + h4.z * w.z + h4.w * w.w;
            w = *(const float4*)(wz + i * 4);
            az += h4.x * w.x + h4.y * w.y + h4.z * w.z + h4.w * w.w;
            w = *(const float4*)(wn + i * 4);
            an += h4.x * w.x + h4.y * w.y + h4.z * w.z + h4.w * w.w;
            w = *(const float4*)(vr + i * 4);
            cr += c4.x * w.x + c4.y * w.y + c4.z * w.z + c4.w * w.w;
            w = *(const float4*)(vz + i * 4);
            cz += c4.x * w.x + c4.y * w.y + c4.z * w.z + c4.w * w.w;
            w = *(const float4*)(vn + i * 4);
            cn += c4.x * w.x + c4.y * w.y + c4.z * w.z + c4.w * w.w;
        }
    } else {
        for (int i = 0; i < 64; ++i) {
            float4 h4 = *(const float4*)(hb + i * 128);
            float4 w;
            w = *(const float4*)(wr + i * 4);
            ar += h4.x * w.x + h4.y * w.y + h4.z * w.z + h4.w * w.w;
            w = *(const float4*)(wz + i * 4);
            az += h4.x * w.x + h4.y * w.y + h4.z * w.z + h4.w * w.w;
            w = *(const float4*)(wn + i * 4);
            an += h4.x * w.x + h4.y * w.y + h4.z * w.z + h4.w * w.w;
        }
    }

    __shared__ float red[6][2][4][32];
    red[0][jl][ks][b] = ar; red[1][jl][ks][b] = az; red[2][jl][ks][b] = an;
    red[3][jl][ks][b] = cr; red[4][jl][ks][b] = cz; red[5][jl][ks][b] = cn;
    __syncthreads();

    if (tid < 64) {
        const int fb = tid & 31;
        const int fj = tid >> 5;
        const int jj = blockIdx.x * 2 + fj;
        float s0 = red[0][fj][0][fb] + red[0][fj][1][fb] + red[0][fj][2][fb] + red[0][fj][3][fb];
        float s1 = red[1][fj][0][fb] + red[1][fj][1][fb] + red[1][fj][2][fb] + red[1][fj][3][fb];
        float s2 = red[2][fj][0][fb] + red[2][fj][1][fb] + red[2][fj][2][fb] + red[2][fj][3][fb];
        float s3 = red[3][fj][0][fb] + red[3][fj][1][fb] + red[3][fj][2][fb] + red[3][fj][3][fb];
        float s4 = red[4][fj][0][fb] + red[4][fj][1][fb] + red[4][fj][2][fb] + red[4][fj][3][fb];
        float s5 = red[5][fj][0][fb] + red[5][fj][1][fb] + red[5][fj][2][fb] + red[5][fj][3][fb];
        const int grow = gi_off + fb * gi_bstride;
        const float* gr = gi + (long)grow * GG;
        float ir  = gr[jj]          + s3;
        float iz  = gr[HH + jj]     + s4;
        float in_ = gr[2 * HH + jj] + s5;
        float hr = s0 + bhh[jj];
        float hz = s1 + bhh[HH + jj];
        float hn = s2 + bhh[2 * HH + jj];
        float r = sigmoid_f(ir + hr);
        float z = sigmoid_f(iz + hz);
        float n = tanh_f(in_ + r * hn);
        float hold = hT4_in[(jj >> 2) * (BB * 4) + fb * 4 + (jj & 3)];
        float hnew = (1.f - z) * n + z * hold;
        hT4_out[(jj >> 2) * (BB * 4) + fb * 4 + (jj & 3)] = hnew;
        extra_out[(long)grow * HH + jj] = hnew;
    }
}

// q[b, j] = hT4(., b) . wq[j, .] + bq[j]
__global__ __launch_bounds__(256) void k_q(
    const float* __restrict__ hT4, const float* __restrict__ wq,
    const float* __restrict__ bq, float* __restrict__ q)
{
    const int tid = threadIdx.x;
    const int b = tid & 31, ks = (tid >> 5) & 3, jl = tid >> 7;
    const int j = blockIdx.x * 2 + jl;
    const int kc = ks * 256;
    const float* hb = hT4 + (kc >> 2) * (BB * 4) + b * 4;
    const float* wr = wq + (long)j * HH + kc;
    float a = 0.f;
    for (int i = 0; i < 64; ++i) {
        float4 h4 = *(const float4*)(hb + i * 128);
        float4 w  = *(const float4*)(wr + i * 4);
        a += h4.x * w.x + h4.y * w.y + h4.z * w.z + h4.w * w.w;
    }
    __shared__ float red[2][4][32];
    red[jl][ks][b] = a;
    __syncthreads();
    if (tid < 64) {
        int fb = tid & 31, fj = tid >> 5, jj = blockIdx.x * 2 + fj;
        float s = red[fj][0][fb] + red[fj][1][fb] + red[fj][2][fb] + red[fj][3][fb] + bq[jj];
        q[(long)fb * HH + jj] = s;
    }
}

// Attention for one decoder step: scores -> masked softmax -> attn weights out + ctx.
// One block per batch element.
__global__ __launch_bounds__(256) void k_attn(
    const float* __restrict__ q, const float* __restrict__ keys,
    const float* __restrict__ wsv, const float* __restrict__ bsv,
    const int* __restrict__ src, const float* __restrict__ enc_out,
    float* __restrict__ ctxT4, float* __restrict__ attn_out, int t)
{
    const int b = blockIdx.x;
    const int tid = threadIdx.x;
    __shared__ float qs[HH];
    __shared__ float wss[HH];
    __shared__ float sc[4][64];
    __shared__ float wl[64];
    for (int i = tid; i < HH; i += 256) {
        qs[i]  = q[(long)b * HH + i];
        wss[i] = wsv[i];
    }
    __syncthreads();

    const int sidx = tid & 63, part = tid >> 6;
    const float* kr = keys + ((long)(b * SS + sidx)) * HH + part * 256;
    float acc = 0.f;
    for (int i = 0; i < 64; ++i) {
        float4 kv = *(const float4*)(kr + i * 4);
        int k = part * 256 + i * 4;
        acc += tanh_f(qs[k    ] + kv.x) * wss[k    ];
        acc += tanh_f(qs[k + 1] + kv.y) * wss[k + 1];
        acc += tanh_f(qs[k + 2] + kv.z) * wss[k + 2];
        acc += tanh_f(qs[k + 3] + kv.w) * wss[k + 3];
    }
    sc[part][sidx] = acc;
    __syncthreads();

    if (tid < 64) {
        float v = sc[0][tid] + sc[1][tid] + sc[2][tid] + sc[3][tid] + bsv[0];
        bool valid = (src[b * SS + tid] != 0);
        float m = valid ? v : -3.0e38f;
        for (int off = 32; off; off >>= 1) m = fmaxf(m, __shfl_xor(m, off));
        float e = valid ? __expf(v - m) : 0.f;
        float ssum = e;
        for (int off = 32; off; off >>= 1) ssum += __shfl_xor(ssum, off);
        float wgt = e / ssum;
        attn_out[((long)b * TD + t) * SS + tid] = wgt;
        wl[tid] = wgt;
    }
    __syncthreads();

    float4 a = make_float4(0.f, 0.f, 0.f, 0.f);
    const float* er = enc_out + (long)b * SS * HH + tid * 4;
    for (int s2 = 0; s2 < SS; ++s2) {
        float wgt = wl[s2];
        float4 ev = *(const float4*)(er + (long)s2 * HH);
        a.x += wgt * ev.x; a.y += wgt * ev.y;
        a.z += wgt * ev.z; a.w += wgt * ev.w;
    }
    *(float4*)(ctxT4 + tid * (BB * 4) + b * 4) = a;
}

extern "C" void kernel_launch(void* const* d_in, const int* in_sizes, int n_in,
                              void* d_out, int out_size, void* d_ws, size_t ws_size,
                              hipStream_t stream)
{
    const int*   src  = (const int*)d_in[0];
    const int*   tgt  = (const int*)d_in[1];
    const float* eemb = (const float*)d_in[2];
    const float* ewih = (const float*)d_in[3];
    const float* ewhh = (const float*)d_in[4];
    const float* ebih = (const float*)d_in[5];
    const float* ebhh = (const float*)d_in[6];
    const float* wq   = (const float*)d_in[7];
    const float* bq   = (const float*)d_in[8];
    const float* wk   = (const float*)d_in[9];
    const float* bk   = (const float*)d_in[10];
    const float* wsv  = (const float*)d_in[11];
    const float* bsv  = (const float*)d_in[12];
    const float* demb = (const float*)d_in[13];
    const float* dwih = (const float*)d_in[14];
    const float* dwhh = (const float*)d_in[15];
    const float* dbih = (const float*)d_in[16];
    const float* dbhh = (const float*)d_in[17];
    const float* wo   = (const float*)d_in[18];
    const float* bo   = (const float*)d_in[19];
    float* out = (float*)d_out;

    float* w = (float*)d_ws;
    float* enc_gi  = w;                                // [B*S][3H]
    float* dec_gi  = enc_gi  + (long)BB * SS * GG;     // [TD*B][3H]
    float* enc_out = dec_gi  + (long)TD * BB * GG;     // [B*S][H]
    float* keys    = enc_out + (long)BB * SS * HH;     // [B*S][H]
    float* h2all   = keys    + (long)BB * SS * HH;     // [TD*B][H]
    float* hA      = h2all   + (long)TD * BB * HH;     // [H/4][B][4]
    float* hB      = hA + BB * HH;
    float* qbuf    = hB + BB * HH;                     // [B][H]
    float* ctxT4   = qbuf + BB * HH;                   // [H/4][B][4]
    int*   didx    = (int*)(ctxT4 + BB * HH);          // [TD*B]

    float* attn_out = out + (long)BB * TD * VV;

    k_zero<<<dim3((BB * HH + 255) / 256), 256, 0, stream>>>(hA, BB * HH);
    k_dec_idx<<<dim3((TD * BB + 255) / 256), 256, 0, stream>>>(tgt, didx);

    // enc_gi = gather(enc_embed)@enc_w_ih^T + b_ih
    k_gemm<<<dim3(GG / 64, (BB * SS) / 64), 256, 0, stream>>>(
        eemb, ewih, ebih, enc_gi, src, BB * SS, GG, EE, EE, EE, GG, 0);
    // dec_gi = gather(dec_embed)@dec_w_ih[:, :E]^T + b_ih
    k_gemm<<<dim3(GG / 64, (TD * BB + 63) / 64), 256, 0, stream>>>(
        demb, dwih, dbih, dec_gi, didx, TD * BB, GG, EE, EE, EE + HH, GG, 0);

    float* cur = hA;
    float* nxt = hB;
    for (int s = 0; s < SS; ++s) {
        k_gru_step<<<dim3(HH / 2), 256, 0, stream>>>(
            cur, nxt, enc_gi, s, SS, ewhh, ebhh, nullptr, nullptr, enc_out);
        float* tmp = cur; cur = nxt; nxt = tmp;
    }

    // keys = enc_out @ wk^T + bk
    k_gemm<<<dim3(HH / 64, (BB * SS) / 64), 256, 0, stream>>>(
        enc_out, wk, bk, keys, nullptr, BB * SS, HH, HH, HH, HH, HH, 0);

    for (int t = 0; t < TD; ++t) {
        k_q<<<dim3(HH / 2), 256, 0, stream>>>(cur, wq, bq, qbuf);
        k_attn<<<dim3(BB), 256, 0, stream>>>(
            qbuf, keys, wsv, bsv, src, enc_out, ctxT4, attn_out, t);
        k_gru_step<<<dim3(HH / 2), 256, 0, stream>>>(
            cur, nxt, dec_gi, t * BB, 1, dwhh, dbhh, ctxT4, dwih, h2all);
        float* tmp = cur; cur = nxt; nxt = tmp;
    }

    // logits = h2all @ wo^T + bo, rows permuted (t*B+b) -> (b*TD+t)
    k_gemm<<<dim3(VV / 64, (TD * BB + 63) / 64), 256, 0, stream>>>(
        h2all, wo, bo, out, nullptr, TD * BB, VV, HH, HH, HH, VV, 1);
}